// Round 5
// baseline (256.173 us; speedup 1.0000x reference)
//
#include <hip/hip_runtime.h>
#include <math.h>

// GeoAttention on gfx950: B=2, S=2048, DIM=512, H=8, HD=64.
// All GEMM stages on bf16 MFMA (16x16x32), fp32 accumulate, operands read as
// contiguous 16B frags from global bf16. R4: branchless software pipelining
// (double frag-register sets) so >=6 loads stay in flight per wave — r4
// counters showed loads serialized (VGPR=56, 1900 cyc/K-iter, all pipes idle).

typedef __attribute__((ext_vector_type(8))) short short8;
typedef __attribute__((ext_vector_type(4))) float f32x4;

#define MFMA(a, b, c) __builtin_amdgcn_mfma_f32_16x16x32_bf16((a), (b), (c), 0, 0, 0)

static __device__ __forceinline__ short f2bf(float f) {
    unsigned u = __float_as_uint(f);
    u += 0x7fffu + ((u >> 16) & 1u);          // round-to-nearest-even
    return (short)(u >> 16);
}

// ---------------------------------------------------------------------------
// Prep 1: xb[4096][1024] bf16 = concat(x_real, x_imag)
// ---------------------------------------------------------------------------
__global__ __launch_bounds__(256) void convert_x(
    const float* __restrict__ xr, const float* __restrict__ xi,
    short* __restrict__ xb)
{
    int idx = blockIdx.x * 256 + threadIdx.x;
    int e = idx << 2;
    int m = e >> 10, k = e & 1023;
    const float* src = (k < 512) ? xr : xi;
    float4 t = *(const float4*)(src + (size_t)m * 512 + (k & 511));
    unsigned lo = (unsigned short)f2bf(t.x) | ((unsigned)(unsigned short)f2bf(t.y) << 16);
    unsigned hi = (unsigned short)f2bf(t.z) | ((unsigned)(unsigned short)f2bf(t.w) << 16);
    uint2 o; o.x = lo; o.y = hi;
    *(uint2*)(xb + e) = o;
}

// ---------------------------------------------------------------------------
// Prep 2: transpose + convert weights to bf16, n-major [N][K].
// ---------------------------------------------------------------------------
__global__ __launch_bounds__(256) void transpose_w(
    const float* __restrict__ Wq, const float* __restrict__ Wk,
    const float* __restrict__ Wv, const float* __restrict__ Wo,
    short* __restrict__ wqt, short* __restrict__ wkt,
    short* __restrict__ wvt, short* __restrict__ wot)
{
    __shared__ float t[32][33];
    const int z = blockIdx.z;
    const float* src = (z == 0) ? Wq : (z == 1) ? Wk : (z == 2) ? Wv : Wo;
    short* dst = (z == 0) ? wqt : (z == 1) ? wkt : (z == 2) ? wvt : wot;
    const int K = (z < 3) ? 1024 : 512;
    const int N = (z < 3) ? 512 : 1024;
    const int n0 = blockIdx.x << 5, k0 = blockIdx.y << 5;
    if (n0 >= N || k0 >= K) return;
    const int tx = threadIdx.x & 31, ty = threadIdx.x >> 5;
    #pragma unroll
    for (int i = 0; i < 4; ++i)
        t[ty + 8 * i][tx] = src[(size_t)(k0 + ty + 8 * i) * N + n0 + tx];
    __syncthreads();
    #pragma unroll
    for (int i = 0; i < 4; ++i)
        dst[(size_t)(n0 + ty + 8 * i) * K + k0 + tx] = f2bf(t[tx][ty + 8 * i]);
}

// ---------------------------------------------------------------------------
// Kernel 1: QKV projection + fused softmax(64)+sqrt epilogue.
// Software-pipelined K-loop: two frag sets, unconditional loads.
// ---------------------------------------------------------------------------
__global__ __launch_bounds__(256) void qkv_mfma(
    const short* __restrict__ xb,
    const short* __restrict__ wqt, const short* __restrict__ wkt,
    const short* __restrict__ wvt,
    const float* __restrict__ bq, const float* __restrict__ bk,
    const float* __restrict__ bv,
    short* __restrict__ sp, short* __restrict__ sq, short* __restrict__ vt)
{
    __shared__ short vbuf[4][64 * 40];        // per-wave [d=64][s=32 +pad8]
    const int iwb = blockIdx.x;
    const int iw = iwb >> 3;
    const int h  = iwb & 7;
    const int m0 = blockIdx.y << 7;
    const int tid = threadIdx.x;
    const int w = tid >> 6, lane = tid & 63;
    const int l = lane & 15, quad = lane >> 4;

    const short* wt   = (iw == 0) ? wqt : (iw == 1) ? wkt : wvt;
    const float* bias = (iw == 0) ? bq  : (iw == 1) ? bk  : bv;
    short* dst        = (iw == 0) ? sp  : (iw == 1) ? sq  : vt;

    const short* a0p = xb + (size_t)(m0 + w * 32 + l) * 1024 + quad * 8;
    const short* a1p = a0p + 16 * 1024;
    const short* bp0 = wt + (size_t)(h * 64 +  0 + l) * 1024 + quad * 8;
    const short* bp1 = wt + (size_t)(h * 64 + 16 + l) * 1024 + quad * 8;
    const short* bp2 = wt + (size_t)(h * 64 + 32 + l) * 1024 + quad * 8;
    const short* bp3 = wt + (size_t)(h * 64 + 48 + l) * 1024 + quad * 8;

    const f32x4 z4 = {0.f, 0.f, 0.f, 0.f};
    f32x4 acc[2][4];
    #pragma unroll
    for (int i = 0; i < 2; ++i)
        #pragma unroll
        for (int j = 0; j < 4; ++j) acc[i][j] = z4;

    short8 A0a = *(const short8*)(a0p), A1a = *(const short8*)(a1p);
    short8 B0a = *(const short8*)(bp0), B1a = *(const short8*)(bp1);
    short8 B2a = *(const short8*)(bp2), B3a = *(const short8*)(bp3);

    #pragma unroll 1
    for (int kc = 0; kc < 32; kc += 2) {
        const int ko1 = (kc + 1) * 32;
        short8 A0b = *(const short8*)(a0p + ko1), A1b = *(const short8*)(a1p + ko1);
        short8 B0b = *(const short8*)(bp0 + ko1), B1b = *(const short8*)(bp1 + ko1);
        short8 B2b = *(const short8*)(bp2 + ko1), B3b = *(const short8*)(bp3 + ko1);

        acc[0][0] = MFMA(A0a, B0a, acc[0][0]);
        acc[1][0] = MFMA(A1a, B0a, acc[1][0]);
        acc[0][1] = MFMA(A0a, B1a, acc[0][1]);
        acc[1][1] = MFMA(A1a, B1a, acc[1][1]);
        acc[0][2] = MFMA(A0a, B2a, acc[0][2]);
        acc[1][2] = MFMA(A1a, B2a, acc[1][2]);
        acc[0][3] = MFMA(A0a, B3a, acc[0][3]);
        acc[1][3] = MFMA(A1a, B3a, acc[1][3]);

        const int ko2 = (kc + 2 < 32) ? (kc + 2) * 32 : 0;   // wrap: harmless re-read
        A0a = *(const short8*)(a0p + ko2); A1a = *(const short8*)(a1p + ko2);
        B0a = *(const short8*)(bp0 + ko2); B1a = *(const short8*)(bp1 + ko2);
        B2a = *(const short8*)(bp2 + ko2); B3a = *(const short8*)(bp3 + ko2);

        acc[0][0] = MFMA(A0b, B0b, acc[0][0]);
        acc[1][0] = MFMA(A1b, B0b, acc[1][0]);
        acc[0][1] = MFMA(A0b, B1b, acc[0][1]);
        acc[1][1] = MFMA(A1b, B1b, acc[1][1]);
        acc[0][2] = MFMA(A0b, B2b, acc[0][2]);
        acc[1][2] = MFMA(A1b, B2b, acc[1][2]);
        acc[0][3] = MFMA(A0b, B3b, acc[0][3]);
        acc[1][3] = MFMA(A1b, B3b, acc[1][3]);
    }

    float bcol[4];
    #pragma unroll
    for (int nt = 0; nt < 4; ++nt) bcol[nt] = bias[h * 64 + nt * 16 + l];

    #pragma unroll
    for (int r16 = 0; r16 < 2; ++r16) {
        #pragma unroll
        for (int reg = 0; reg < 4; ++reg) {
            const int sg = m0 + w * 32 + r16 * 16 + quad * 4 + reg;  // global row
            const int b = sg >> 11, s = sg & 2047;
            float v[4];
            #pragma unroll
            for (int nt = 0; nt < 4; ++nt) v[nt] = acc[r16][nt][reg] + bcol[nt];
            if (iw < 2) {
                float mx = fmaxf(fmaxf(v[0], v[1]), fmaxf(v[2], v[3]));
                #pragma unroll
                for (int msk = 1; msk < 16; msk <<= 1) mx = fmaxf(mx, __shfl_xor(mx, msk));
                float e[4], ssum = 0.f;
                #pragma unroll
                for (int nt = 0; nt < 4; ++nt) { e[nt] = __expf(v[nt] - mx); ssum += e[nt]; }
                #pragma unroll
                for (int msk = 1; msk < 16; msk <<= 1) ssum += __shfl_xor(ssum, msk);
                float inv = 1.0f / ssum;
                short* o = dst + ((size_t)(b * 8 + h) * 2048 + s) * 64 + l;
                #pragma unroll
                for (int nt = 0; nt < 4; ++nt)
                    o[nt * 16] = f2bf(sqrtf(e[nt] * inv));
            } else {
                const int sl = r16 * 16 + quad * 4 + reg;   // local s in [0,32)
                #pragma unroll
                for (int nt = 0; nt < 4; ++nt)
                    vbuf[w][(nt * 16 + l) * 40 + sl] = f2bf(v[nt]);
            }
        }
    }

    if (iw == 2) {
        // wave-synchronous readback: lane d -> 32 contiguous s, 16B stores
        const int d = lane;
        const short* row = &vbuf[w][d * 40];
        short8 r0 = *(const short8*)(row);
        short8 r1 = *(const short8*)(row + 8);
        short8 r2 = *(const short8*)(row + 16);
        short8 r3 = *(const short8*)(row + 24);
        const int sg0 = m0 + w * 32;
        const int b = sg0 >> 11, s0 = sg0 & 2047;
        short* gp = vt + ((size_t)(b * 8 + h) * 64 + d) * 2048 + s0;
        *(short8*)(gp)      = r0;
        *(short8*)(gp + 8)  = r1;
        *(short8*)(gp + 16) = r2;
        *(short8*)(gp + 24) = r3;
    }
}

// ---------------------------------------------------------------------------
// Kernel 2: attention. Grid (32, 16), 512 threads = 8 waves.
// Block = 64 Q-rows: wave w -> rowgroup rg=w>>2 (32 rows), j-split js=w&3.
// Pipelined: V-frags for jt issued before QK+transform (drain under VALU);
// sq-frags for jt+1 issued before PV (branchless wrap). Wave-private LDS P.
// ---------------------------------------------------------------------------
__global__ __launch_bounds__(512) void attn_mfma(
    const short* __restrict__ sp, const short* __restrict__ sq,
    const short* __restrict__ vt, short* __restrict__ attB)
{
    __shared__ short Ps[8][32 * 72];            // 36,864 B
    __shared__ float denB[8][32];               // 1 KB
    const int bh = blockIdx.y;
    const int tid = threadIdx.x;
    const int w = tid >> 6, lane = tid & 63;
    const int rg = w >> 2, js = w & 3;
    const int l = lane & 15, quad = lane >> 4;
    const int m0 = (blockIdx.x << 6) + rg * 32;

    const short* spB = sp + (size_t)bh * 2048 * 64;
    const short* sqB = sq + (size_t)bh * 2048 * 64 + (size_t)(js * 512) * 64;
    const short* vtB = vt + (size_t)bh * 64 * 2048 + js * 512;
    short* P = &Ps[w][0];

    const short* ap0 = spB + (size_t)(m0 + l) * 64 + quad * 8;
    const short* ap1 = spB + (size_t)(m0 + 16 + l) * 64 + quad * 8;
    short8 a00 = *(const short8*)(ap0);
    short8 a01 = *(const short8*)(ap0 + 32);
    short8 a10 = *(const short8*)(ap1);
    short8 a11 = *(const short8*)(ap1 + 32);

    const f32x4 z4 = {0.f, 0.f, 0.f, 0.f};
    f32x4 acc[2][4];
    float den[2][4];
    #pragma unroll
    for (int s = 0; s < 2; ++s)
        #pragma unroll
        for (int j = 0; j < 4; ++j) { acc[s][j] = z4; den[s][j] = 0.f; }

    // preload sq frags for jt=0
    short8 sqb[4][2];
    #pragma unroll
    for (int nt = 0; nt < 4; ++nt) {
        const short* q = sqB + (size_t)(nt * 16 + l) * 64 + quad * 8;
        sqb[nt][0] = *(const short8*)(q);
        sqb[nt][1] = *(const short8*)(q + 32);
    }

    #pragma unroll 1
    for (int jt = 0; jt < 8; ++jt) {
        // issue V loads now; consumed only after QK + transform (latency hidden)
        short8 vtb[4][2];
        const short* vj = vtB + jt * 64;
        #pragma unroll
        for (int nt = 0; nt < 4; ++nt) {
            const short* q = vj + (size_t)(nt * 16 + l) * 2048 + quad * 8;
            vtb[nt][0] = *(const short8*)(q);
            vtb[nt][1] = *(const short8*)(q + 32);
        }

        // QK^T + transform + P stores
        #pragma unroll
        for (int nt = 0; nt < 4; ++nt) {
            #pragma unroll
            for (int s = 0; s < 2; ++s) {
                f32x4 p = MFMA(s ? a10 : a00, sqb[nt][0], z4);
                p = MFMA(s ? a11 : a01, sqb[nt][1], p);
                #pragma unroll
                for (int reg = 0; reg < 4; ++reg) {
                    // bc in [0,1]; acos(x)^2 = 2u + u^2/3 + ..., u = 1-x
                    float u = fmaxf(1.0f - p[reg], 0.0f);
                    float t = 0.000922f;
                    t = fmaf(t, u, 0.00152228f);
                    t = fmaf(t, u, 0.00384801f);
                    t = fmaf(t, u, 0.01015873f);
                    t = fmaf(t, u, 0.02857143f);
                    t = fmaf(t, u, 0.08888889f);
                    t = fmaf(t, u, 0.33333333f);
                    t = fmaf(t, u, 2.0f);
                    float d2 = u * t;
                    float wv = __expf(-d2);
                    den[s][reg] += wv;
                    P[(s * 16 + quad * 4 + reg) * 72 + nt * 16 + l] = f2bf(wv);
                }
            }
        }

        // prefetch sq frags for jt+1 (wraps to 0: harmless re-read)
        const short* sqn = sqB + (size_t)(((jt + 1) & 7) * 64) * 64;
        #pragma unroll
        for (int nt = 0; nt < 4; ++nt) {
            const short* q = sqn + (size_t)(nt * 16 + l) * 64 + quad * 8;
            sqb[nt][0] = *(const short8*)(q);
            sqb[nt][1] = *(const short8*)(q + 32);
        }

        // P rows -> A-frags (bf16, stride-72 rows are 16B aligned)
        short8 pa[2][2];
        #pragma unroll
        for (int s = 0; s < 2; ++s) {
            const short* pr = P + (s * 16 + l) * 72 + quad * 8;
            pa[s][0] = *(const short8*)(pr);
            pa[s][1] = *(const short8*)(pr + 32);
        }
        // PV
        #pragma unroll
        for (int nt = 0; nt < 4; ++nt)
            #pragma unroll
            for (int s = 0; s < 2; ++s) {
                acc[s][nt] = MFMA(pa[s][0], vtb[nt][0], acc[s][nt]);
                acc[s][nt] = MFMA(pa[s][1], vtb[nt][1], acc[s][nt]);
            }
    }

    // reduce den over the 16 l-lanes of each quad; store per-wave
    #pragma unroll
    for (int s = 0; s < 2; ++s)
        #pragma unroll
        for (int reg = 0; reg < 4; ++reg) {
            float sm = den[s][reg];
            #pragma unroll
            for (int msk = 1; msk < 16; msk <<= 1) sm += __shfl_xor(sm, msk);
            if (l == 0) denB[w][s * 16 + quad * 4 + reg] = sm;
        }

    __syncthreads();
    // two-phase fp32 combine reusing Ps memory (4 x 2176 floats = 34.8 KB)
    float* Cb = (float*)&Ps[0][0];
    const int b = bh >> 3, hh = bh & 7;
    #pragma unroll
    for (int ph = 0; ph < 2; ++ph) {
        if (rg == ph) {
            float* Cw = Cb + js * 2176;
            #pragma unroll
            for (int s = 0; s < 2; ++s)
                #pragma unroll
                for (int nt = 0; nt < 4; ++nt)
                    #pragma unroll
                    for (int reg = 0; reg < 4; ++reg)
                        Cw[(s * 16 + quad * 4 + reg) * 68 + nt * 16 + l] = acc[s][nt][reg];
        }
        __syncthreads();
        if (rg == ph) {
            #pragma unroll
            for (int half = 0; half < 2; ++half)
                #pragma unroll
                for (int reg = 0; reg < 4; ++reg) {
                    const int row = half * 16 + quad * 4 + reg;
                    float num = 0.f, dt = 0.f;
                    #pragma unroll
                    for (int s2 = 0; s2 < 4; ++s2) {
                        num += Cb[s2 * 2176 + row * 68 + js * 16 + l];
                        dt  += denB[rg * 4 + s2][row];
                    }
                    const int srow = (blockIdx.x << 6) + rg * 32 + row;
                    attB[((size_t)(b * 2048 + srow)) * 512 + hh * 64 + js * 16 + l] =
                        f2bf(num / dt);
                }
        }
        __syncthreads();
    }
}

// ---------------------------------------------------------------------------
// Kernel 3: out = attB[4096][512](bf16) @ Wo + bo -> fp32, pipelined K-loop.
// ---------------------------------------------------------------------------
__global__ __launch_bounds__(256) void out_mfma(
    const short* __restrict__ attB, const short* __restrict__ wot,
    const float* __restrict__ bo, float* __restrict__ out)
{
    const int n0 = blockIdx.x << 6;
    const int m0 = blockIdx.y << 7;
    const int tid = threadIdx.x;
    const int w = tid >> 6, lane = tid & 63;
    const int l = lane & 15, quad = lane >> 4;

    const short* a0p = attB + (size_t)(m0 + w * 32 + l) * 512 + quad * 8;
    const short* a1p = a0p + 16 * 512;
    const short* bp0 = wot + (size_t)(n0 +  0 + l) * 512 + quad * 8;
    const short* bp1 = wot + (size_t)(n0 + 16 + l) * 512 + quad * 8;
    const short* bp2 = wot + (size_t)(n0 + 32 + l) * 512 + quad * 8;
    const short* bp3 = wot + (size_t)(n0 + 48 + l) * 512 + quad * 8;

    const f32x4 z4 = {0.f, 0.f, 0.f, 0.f};
    f32x4 acc[2][4];
    #pragma unroll
    for (int i = 0; i < 2; ++i)
        #pragma unroll
        for (int j = 0; j < 4; ++j) acc[i][j] = z4;

    short8 A0a = *(const short8*)(a0p), A1a = *(const short8*)(a1p);
    short8 B0a = *(const short8*)(bp0), B1a = *(const short8*)(bp1);
    short8 B2a = *(const short8*)(bp2), B3a = *(const short8*)(bp3);

    #pragma unroll 1
    for (int kc = 0; kc < 16; kc += 2) {
        const int ko1 = (kc + 1) * 32;
        short8 A0b = *(const short8*)(a0p + ko1), A1b = *(const short8*)(a1p + ko1);
        short8 B0b = *(const short8*)(bp0 + ko1), B1b = *(const short8*)(bp1 + ko1);
        short8 B2b = *(const short8*)(bp2 + ko1), B3b = *(const short8*)(bp3 + ko1);

        acc[0][0] = MFMA(A0a, B0a, acc[0][0]);
        acc[1][0] = MFMA(A1a, B0a, acc[1][0]);
        acc[0][1] = MFMA(A0a, B1a, acc[0][1]);
        acc[1][1] = MFMA(A1a, B1a, acc[1][1]);
        acc[0][2] = MFMA(A0a, B2a, acc[0][2]);
        acc[1][2] = MFMA(A1a, B2a, acc[1][2]);
        acc[0][3] = MFMA(A0a, B3a, acc[0][3]);
        acc[1][3] = MFMA(A1a, B3a, acc[1][3]);

        const int ko2 = (kc + 2 < 16) ? (kc + 2) * 32 : 0;   // wrap: harmless
        A0a = *(const short8*)(a0p + ko2); A1a = *(const short8*)(a1p + ko2);
        B0a = *(const short8*)(bp0 + ko2); B1a = *(const short8*)(bp1 + ko2);
        B2a = *(const short8*)(bp2 + ko2); B3a = *(const short8*)(bp3 + ko2);

        acc[0][0] = MFMA(A0b, B0b, acc[0][0]);
        acc[1][0] = MFMA(A1b, B0b, acc[1][0]);
        acc[0][1] = MFMA(A0b, B1b, acc[0][1]);
        acc[1][1] = MFMA(A1b, B1b, acc[1][1]);
        acc[0][2] = MFMA(A0b, B2b, acc[0][2]);
        acc[1][2] = MFMA(A1b, B2b, acc[1][2]);
        acc[0][3] = MFMA(A0b, B3b, acc[0][3]);
        acc[1][3] = MFMA(A1b, B3b, acc[1][3]);
    }

    #pragma unroll
    for (int r16 = 0; r16 < 2; ++r16)
        #pragma unroll
        for (int reg = 0; reg < 4; ++reg) {
            const int m = m0 + w * 32 + r16 * 16 + quad * 4 + reg;
            float* o = out + (size_t)m * 1024 + n0 + l;
            #pragma unroll
            for (int nt = 0; nt < 4; ++nt)
                o[nt * 16] = acc[r16][nt][reg] + bo[n0 + nt * 16 + l];
        }
}

// ---------------------------------------------------------------------------
extern "C" void kernel_launch(void* const* d_in, const int* in_sizes, int n_in,
                              void* d_out, int out_size, void* d_ws, size_t ws_size,
                              hipStream_t stream) {
    const float* xr = (const float*)d_in[0];
    const float* xi = (const float*)d_in[1];
    const float* Wq = (const float*)d_in[2];
    const float* bq = (const float*)d_in[3];
    const float* Wk = (const float*)d_in[4];
    const float* bk = (const float*)d_in[5];
    const float* Wv = (const float*)d_in[6];
    const float* bv = (const float*)d_in[7];
    const float* Wo = (const float*)d_in[8];
    const float* bo = (const float*)d_in[9];
    float* out = (float*)d_out;

    short* base = (short*)d_ws;
    short* xb   = base;                      // 4096*1024
    short* wqt  = xb  + 4194304;             // 512*1024
    short* wkt  = wqt + 524288;
    short* wvt  = wkt + 524288;
    short* wot  = wvt + 524288;              // 1024*512
    short* spW  = wot + 524288;              // 16*2048*64
    short* sqW  = spW + 2097152;
    short* vtW  = sqW + 2097152;             // [b,h,d,s]
    short* attB = vtW + 2097152;             // 4096*512
    // total = 14,680,064 shorts = 28 MB

    hipLaunchKernelGGL(convert_x, dim3(4096), dim3(256), 0, stream, xr, xi, xb);
    hipLaunchKernelGGL(transpose_w, dim3(32, 32, 4), dim3(256), 0, stream,
                       Wq, Wk, Wv, Wo, wqt, wkt, wvt, wot);
    hipLaunchKernelGGL(qkv_mfma, dim3(24, 32), dim3(256), 0, stream,
                       xb, wqt, wkt, wvt, bq, bk, bv, spW, sqW, vtW);
    hipLaunchKernelGGL(attn_mfma, dim3(32, 16), dim3(512), 0, stream,
                       spW, sqW, vtW, attB);
    hipLaunchKernelGGL(out_mfma, dim3(16, 32), dim3(256), 0, stream,
                       attB, wot, bo, out);
}

// Round 6
// 232.276 us; speedup vs baseline: 1.1029x; 1.1029x over previous
//
#include <hip/hip_runtime.h>
#include <math.h>

// GeoAttention on gfx950: B=2, S=2048, DIM=512, H=8, HD=64.
// bf16 MFMA (16x16x32) everywhere, fp32 accumulate.
// R5: qkv/out use 64x64 wave tiles (16 MFMA : 8 loads); attn uses 4-wave
// blocks (1024 blocks), per-jt phase interleave, inline V loads, truncating
// P-pack, two-phase fp32 combine in reused LDS.

typedef __attribute__((ext_vector_type(8))) short short8;
typedef __attribute__((ext_vector_type(4))) float f32x4;

#define MFMA(a, b, c) __builtin_amdgcn_mfma_f32_16x16x32_bf16((a), (b), (c), 0, 0, 0)

static __device__ __forceinline__ short f2bf(float f) {
    unsigned u = __float_as_uint(f);
    u += 0x7fffu + ((u >> 16) & 1u);          // round-to-nearest-even
    return (short)(u >> 16);
}
static __device__ __forceinline__ short f2bf_trunc(float f) {
    return (short)(__float_as_uint(f) >> 16); // bias cancels in num/den ratio
}

// ---------------------------------------------------------------------------
// Prep 1: xb[4096][1024] bf16 = concat(x_real, x_imag)
// ---------------------------------------------------------------------------
__global__ __launch_bounds__(256) void convert_x(
    const float* __restrict__ xr, const float* __restrict__ xi,
    short* __restrict__ xb)
{
    int idx = blockIdx.x * 256 + threadIdx.x;
    int e = idx << 2;
    int m = e >> 10, k = e & 1023;
    const float* src = (k < 512) ? xr : xi;
    float4 t = *(const float4*)(src + (size_t)m * 512 + (k & 511));
    unsigned lo = (unsigned short)f2bf(t.x) | ((unsigned)(unsigned short)f2bf(t.y) << 16);
    unsigned hi = (unsigned short)f2bf(t.z) | ((unsigned)(unsigned short)f2bf(t.w) << 16);
    uint2 o; o.x = lo; o.y = hi;
    *(uint2*)(xb + e) = o;
}

// ---------------------------------------------------------------------------
// Prep 2: transpose + convert weights to bf16, n-major [N][K].
// ---------------------------------------------------------------------------
__global__ __launch_bounds__(256) void transpose_w(
    const float* __restrict__ Wq, const float* __restrict__ Wk,
    const float* __restrict__ Wv, const float* __restrict__ Wo,
    short* __restrict__ wqt, short* __restrict__ wkt,
    short* __restrict__ wvt, short* __restrict__ wot)
{
    __shared__ float t[32][33];
    const int z = blockIdx.z;
    const float* src = (z == 0) ? Wq : (z == 1) ? Wk : (z == 2) ? Wv : Wo;
    short* dst = (z == 0) ? wqt : (z == 1) ? wkt : (z == 2) ? wvt : wot;
    const int K = (z < 3) ? 1024 : 512;
    const int N = (z < 3) ? 512 : 1024;
    const int n0 = blockIdx.x << 5, k0 = blockIdx.y << 5;
    if (n0 >= N || k0 >= K) return;
    const int tx = threadIdx.x & 31, ty = threadIdx.x >> 5;
    #pragma unroll
    for (int i = 0; i < 4; ++i)
        t[ty + 8 * i][tx] = src[(size_t)(k0 + ty + 8 * i) * N + n0 + tx];
    __syncthreads();
    #pragma unroll
    for (int i = 0; i < 4; ++i)
        dst[(size_t)(n0 + ty + 8 * i) * K + k0 + tx] = f2bf(t[tx][ty + 8 * i]);
}

// ---------------------------------------------------------------------------
// Kernel 1: QKV projection + fused softmax(64)+sqrt epilogue.
// 128-thr blocks = 2 waves; wave = 64 rows x 64 cols (16 MFMA per 8 loads).
// Grid (24, 32). V bounced through LDS to transposed [b,h,d,s] layout.
// ---------------------------------------------------------------------------
__global__ __launch_bounds__(128) void qkv_mfma(
    const short* __restrict__ xb,
    const short* __restrict__ wqt, const short* __restrict__ wkt,
    const short* __restrict__ wvt,
    const float* __restrict__ bq, const float* __restrict__ bk,
    const float* __restrict__ bv,
    short* __restrict__ sp, short* __restrict__ sq, short* __restrict__ vt)
{
    __shared__ short vbuf[2][64 * 72];        // per-wave [d=64][s=64 +pad8]
    const int iwb = blockIdx.x;
    const int iw = iwb >> 3;
    const int h  = iwb & 7;
    const int tid = threadIdx.x;
    const int w = tid >> 6, lane = tid & 63;
    const int l = lane & 15, quad = lane >> 4;
    const int m0 = blockIdx.y * 128 + w * 64;

    const short* wt   = (iw == 0) ? wqt : (iw == 1) ? wkt : wvt;
    const float* bias = (iw == 0) ? bq  : (iw == 1) ? bk  : bv;
    short* dst        = (iw == 0) ? sp  : (iw == 1) ? sq  : vt;

    const short* ap[4];
    const short* bp[4];
    #pragma unroll
    for (int i = 0; i < 4; ++i)
        ap[i] = xb + (size_t)(m0 + i * 16 + l) * 1024 + quad * 8;
    #pragma unroll
    for (int j = 0; j < 4; ++j)
        bp[j] = wt + (size_t)(h * 64 + j * 16 + l) * 1024 + quad * 8;

    const f32x4 z4 = {0.f, 0.f, 0.f, 0.f};
    f32x4 acc[4][4];
    #pragma unroll
    for (int i = 0; i < 4; ++i)
        #pragma unroll
        for (int j = 0; j < 4; ++j) acc[i][j] = z4;

    short8 Af[4], Bf[4], Ag[4], Bg[4];
    #pragma unroll
    for (int i = 0; i < 4; ++i) { Af[i] = *(const short8*)ap[i]; Bf[i] = *(const short8*)bp[i]; }

    #pragma unroll 1
    for (int kc = 0; kc < 32; kc += 2) {
        const int ko1 = (kc + 1) * 32;
        #pragma unroll
        for (int i = 0; i < 4; ++i) {
            Ag[i] = *(const short8*)(ap[i] + ko1);
            Bg[i] = *(const short8*)(bp[i] + ko1);
        }
        #pragma unroll
        for (int i = 0; i < 4; ++i)
            #pragma unroll
            for (int j = 0; j < 4; ++j)
                acc[i][j] = MFMA(Af[i], Bf[j], acc[i][j]);
        const int ko2 = (kc + 2 < 32) ? (kc + 2) * 32 : 0;   // wrap: harmless
        #pragma unroll
        for (int i = 0; i < 4; ++i) {
            Af[i] = *(const short8*)(ap[i] + ko2);
            Bf[i] = *(const short8*)(bp[i] + ko2);
        }
        #pragma unroll
        for (int i = 0; i < 4; ++i)
            #pragma unroll
            for (int j = 0; j < 4; ++j)
                acc[i][j] = MFMA(Ag[i], Bg[j], acc[i][j]);
    }

    float bcol[4];
    #pragma unroll
    for (int nt = 0; nt < 4; ++nt) bcol[nt] = bias[h * 64 + nt * 16 + l];

    #pragma unroll
    for (int i = 0; i < 4; ++i) {
        #pragma unroll
        for (int reg = 0; reg < 4; ++reg) {
            const int sg = m0 + i * 16 + quad * 4 + reg;     // global row
            const int b = sg >> 11, s = sg & 2047;
            float v[4];
            #pragma unroll
            for (int nt = 0; nt < 4; ++nt) v[nt] = acc[i][nt][reg] + bcol[nt];
            if (iw < 2) {
                float mx = fmaxf(fmaxf(v[0], v[1]), fmaxf(v[2], v[3]));
                #pragma unroll
                for (int msk = 1; msk < 16; msk <<= 1) mx = fmaxf(mx, __shfl_xor(mx, msk));
                float e[4], ssum = 0.f;
                #pragma unroll
                for (int nt = 0; nt < 4; ++nt) { e[nt] = __expf(v[nt] - mx); ssum += e[nt]; }
                #pragma unroll
                for (int msk = 1; msk < 16; msk <<= 1) ssum += __shfl_xor(ssum, msk);
                float inv = 1.0f / ssum;
                short* o = dst + ((size_t)(b * 8 + h) * 2048 + s) * 64 + l;
                #pragma unroll
                for (int nt = 0; nt < 4; ++nt)
                    o[nt * 16] = f2bf(sqrtf(e[nt] * inv));
            } else {
                const int sl = i * 16 + quad * 4 + reg;      // local s in [0,64)
                #pragma unroll
                for (int nt = 0; nt < 4; ++nt)
                    vbuf[w][(nt * 16 + l) * 72 + sl] = f2bf(v[nt]);
            }
        }
    }

    if (iw == 2) {
        // wave-synchronous readback: lane d -> 64 contiguous s, 16B stores
        const int d = lane;
        const short* row = &vbuf[w][d * 72];
        const int b = m0 >> 11, s0 = m0 & 2047;
        short* gp = vt + ((size_t)(b * 8 + h) * 64 + d) * 2048 + s0;
        #pragma unroll
        for (int r = 0; r < 8; ++r)
            *(short8*)(gp + r * 8) = *(const short8*)(row + r * 8);
    }
}

// ---------------------------------------------------------------------------
// Kernel 2: attention. Grid (64, 16), 256 threads = 4 waves.
// Block = 32 Q-rows; wave w = j-split js (512 j each, 8 jt of 64).
// Per jt: QK(s0)->transform(s0) | QK(s1)->sq-prefetch->transform(s1) |
// pa LDS read | PV with inline V loads. fp32 combine in 2 strip-phases.
// ---------------------------------------------------------------------------
__global__ __launch_bounds__(256) void attn_mfma(
    const short* __restrict__ sp, const short* __restrict__ sq,
    const short* __restrict__ vt, short* __restrict__ attB)
{
    __shared__ short Ps[4][32 * 72];            // 18,432 B (bf16 P; fp32 combine reuse)
    __shared__ float denB[4][32];               // 512 B
    const int bh = blockIdx.y;
    const int m0 = blockIdx.x << 5;
    const int tid = threadIdx.x;
    const int w = tid >> 6, lane = tid & 63;
    const int js = w;
    const int l = lane & 15, quad = lane >> 4;

    const short* spB = sp + (size_t)bh * 2048 * 64;
    const short* sqB = sq + (size_t)bh * 2048 * 64 + (size_t)(js * 512) * 64;
    const short* vtB = vt + (size_t)bh * 64 * 2048 + js * 512;
    short* P = &Ps[w][0];

    const short* ap0 = spB + (size_t)(m0 + l) * 64 + quad * 8;
    const short* ap1 = ap0 + 16 * 64;
    short8 a00 = *(const short8*)(ap0);
    short8 a01 = *(const short8*)(ap0 + 32);
    short8 a10 = *(const short8*)(ap1);
    short8 a11 = *(const short8*)(ap1 + 32);

    const f32x4 z4 = {0.f, 0.f, 0.f, 0.f};
    f32x4 acc[2][4];
    float den[2][4];
    #pragma unroll
    for (int s = 0; s < 2; ++s)
        #pragma unroll
        for (int j = 0; j < 4; ++j) { acc[s][j] = z4; den[s][j] = 0.f; }

    // preload sq frags for jt=0
    short8 sqb[4][2];
    #pragma unroll
    for (int nt = 0; nt < 4; ++nt) {
        const short* q = sqB + (size_t)(nt * 16 + l) * 64 + quad * 8;
        sqb[nt][0] = *(const short8*)(q);
        sqb[nt][1] = *(const short8*)(q + 32);
    }

    #pragma unroll 1
    for (int jt = 0; jt < 8; ++jt) {
        // strip 0: QK + transform
        #pragma unroll
        for (int nt = 0; nt < 4; ++nt) {
            f32x4 p = MFMA(a00, sqb[nt][0], z4);
            p = MFMA(a01, sqb[nt][1], p);
            #pragma unroll
            for (int reg = 0; reg < 4; ++reg) {
                float u = fmaxf(1.0f - p[reg], 0.0f);
                float t = 0.000922f;
                t = fmaf(t, u, 0.00152228f);
                t = fmaf(t, u, 0.00384801f);
                t = fmaf(t, u, 0.01015873f);
                t = fmaf(t, u, 0.02857143f);
                t = fmaf(t, u, 0.08888889f);
                t = fmaf(t, u, 0.33333333f);
                t = fmaf(t, u, 2.0f);
                float wv = __expf(-u * t);
                den[0][reg] += wv;
                P[(quad * 4 + reg) * 72 + nt * 16 + l] = f2bf_trunc(wv);
            }
        }
        // strip 1: QK, then sqb[nt] is dead -> prefetch jt+1, then transform
        const short* sqn = sqB + (size_t)(((jt + 1) & 7) * 64) * 64;
        #pragma unroll
        for (int nt = 0; nt < 4; ++nt) {
            f32x4 p = MFMA(a10, sqb[nt][0], z4);
            p = MFMA(a11, sqb[nt][1], p);
            {
                const short* q = sqn + (size_t)(nt * 16 + l) * 64 + quad * 8;
                sqb[nt][0] = *(const short8*)(q);
                sqb[nt][1] = *(const short8*)(q + 32);
            }
            #pragma unroll
            for (int reg = 0; reg < 4; ++reg) {
                float u = fmaxf(1.0f - p[reg], 0.0f);
                float t = 0.000922f;
                t = fmaf(t, u, 0.00152228f);
                t = fmaf(t, u, 0.00384801f);
                t = fmaf(t, u, 0.01015873f);
                t = fmaf(t, u, 0.02857143f);
                t = fmaf(t, u, 0.08888889f);
                t = fmaf(t, u, 0.33333333f);
                t = fmaf(t, u, 2.0f);
                float wv = __expf(-u * t);
                den[1][reg] += wv;
                P[(16 + quad * 4 + reg) * 72 + nt * 16 + l] = f2bf_trunc(wv);
            }
        }
        // P rows -> A-frags (stride-72 rows: 144B, 16B-aligned)
        short8 pa[2][2];
        #pragma unroll
        for (int s = 0; s < 2; ++s) {
            const short* pr = P + (s * 16 + l) * 72 + quad * 8;
            pa[s][0] = *(const short8*)(pr);
            pa[s][1] = *(const short8*)(pr + 32);
        }
        // PV with inline V loads (vt slice is L2-hot: shared by 64 blocks)
        const short* vj = vtB + jt * 64;
        #pragma unroll
        for (int nt = 0; nt < 4; ++nt) {
            const short* q = vj + (size_t)(nt * 16 + l) * 2048 + quad * 8;
            short8 b0 = *(const short8*)(q);
            short8 b1 = *(const short8*)(q + 32);
            acc[0][nt] = MFMA(pa[0][0], b0, acc[0][nt]);
            acc[0][nt] = MFMA(pa[0][1], b1, acc[0][nt]);
            acc[1][nt] = MFMA(pa[1][0], b0, acc[1][nt]);
            acc[1][nt] = MFMA(pa[1][1], b1, acc[1][nt]);
        }
    }

    // den: reduce over the 16 l-lanes of each quad; publish per wave
    #pragma unroll
    for (int s = 0; s < 2; ++s)
        #pragma unroll
        for (int reg = 0; reg < 4; ++reg) {
            float sm = den[s][reg];
            #pragma unroll
            for (int msk = 1; msk < 16; msk <<= 1) sm += __shfl_xor(sm, msk);
            if (l == 0) denB[w][s * 16 + quad * 4 + reg] = sm;
        }
    __syncthreads();

    // two strip-phases of fp32 combine reusing Ps (4 x 1088 floats = 17.4 KB)
    float* Cb = (float*)&Ps[0][0];
    const int b = bh >> 3, hh = bh & 7;
    #pragma unroll
    for (int s = 0; s < 2; ++s) {
        float* Cw = Cb + js * 1088;
        #pragma unroll
        for (int nt = 0; nt < 4; ++nt)
            #pragma unroll
            for (int reg = 0; reg < 4; ++reg)
                Cw[(quad * 4 + reg) * 68 + nt * 16 + l] = acc[s][nt][reg];
        __syncthreads();
        #pragma unroll
        for (int reg = 0; reg < 4; ++reg) {
            const int row = quad * 4 + reg;
            float num = 0.f, dt = 0.f;
            #pragma unroll
            for (int s2 = 0; s2 < 4; ++s2) {
                num += Cb[s2 * 1088 + row * 68 + js * 16 + l];
                dt  += denB[s2][s * 16 + row];
            }
            const int srow = m0 + s * 16 + row;
            attB[((size_t)(b * 2048 + srow)) * 512 + hh * 64 + js * 16 + l] =
                f2bf(num / dt);
        }
        __syncthreads();
    }
}

// ---------------------------------------------------------------------------
// Kernel 3: out = attB[4096][512](bf16) @ Wo + bo -> fp32 [4096][1024]
// 128-thr blocks = 2 waves; wave = 64x64 tile. Grid (16, 32).
// ---------------------------------------------------------------------------
__global__ __launch_bounds__(128) void out_mfma(
    const short* __restrict__ attB, const short* __restrict__ wot,
    const float* __restrict__ bo, float* __restrict__ out)
{
    const int n0 = blockIdx.x << 6;
    const int tid = threadIdx.x;
    const int w = tid >> 6, lane = tid & 63;
    const int l = lane & 15, quad = lane >> 4;
    const int m0 = blockIdx.y * 128 + w * 64;

    const short* ap[4];
    const short* bp[4];
    #pragma unroll
    for (int i = 0; i < 4; ++i)
        ap[i] = attB + (size_t)(m0 + i * 16 + l) * 512 + quad * 8;
    #pragma unroll
    for (int j = 0; j < 4; ++j)
        bp[j] = wot + (size_t)(n0 + j * 16 + l) * 512 + quad * 8;

    const f32x4 z4 = {0.f, 0.f, 0.f, 0.f};
    f32x4 acc[4][4];
    #pragma unroll
    for (int i = 0; i < 4; ++i)
        #pragma unroll
        for (int j = 0; j < 4; ++j) acc[i][j] = z4;

    short8 Af[4], Bf[4], Ag[4], Bg[4];
    #pragma unroll
    for (int i = 0; i < 4; ++i) { Af[i] = *(const short8*)ap[i]; Bf[i] = *(const short8*)bp[i]; }

    #pragma unroll 1
    for (int kc = 0; kc < 16; kc += 2) {
        const int ko1 = (kc + 1) * 32;
        #pragma unroll
        for (int i = 0; i < 4; ++i) {
            Ag[i] = *(const short8*)(ap[i] + ko1);
            Bg[i] = *(const short8*)(bp[i] + ko1);
        }
        #pragma unroll
        for (int i = 0; i < 4; ++i)
            #pragma unroll
            for (int j = 0; j < 4; ++j)
                acc[i][j] = MFMA(Af[i], Bf[j], acc[i][j]);
        const int ko2 = (kc + 2 < 16) ? (kc + 2) * 32 : 0;   // wrap: harmless
        #pragma unroll
        for (int i = 0; i < 4; ++i) {
            Af[i] = *(const short8*)(ap[i] + ko2);
            Bf[i] = *(const short8*)(bp[i] + ko2);
        }
        #pragma unroll
        for (int i = 0; i < 4; ++i)
            #pragma unroll
            for (int j = 0; j < 4; ++j)
                acc[i][j] = MFMA(Ag[i], Bg[j], acc[i][j]);
    }

    #pragma unroll
    for (int i = 0; i < 4; ++i)
        #pragma unroll
        for (int reg = 0; reg < 4; ++reg) {
            const int m = m0 + i * 16 + quad * 4 + reg;
            float* o = out + (size_t)m * 1024 + n0 + l;
            #pragma unroll
            for (int nt = 0; nt < 4; ++nt)
                o[nt * 16] = acc[i][nt][reg] + bo[n0 + nt * 16 + l];
        }
}

// ---------------------------------------------------------------------------
extern "C" void kernel_launch(void* const* d_in, const int* in_sizes, int n_in,
                              void* d_out, int out_size, void* d_ws, size_t ws_size,
                              hipStream_t stream) {
    const float* xr = (const float*)d_in[0];
    const float* xi = (const float*)d_in[1];
    const float* Wq = (const float*)d_in[2];
    const float* bq = (const float*)d_in[3];
    const float* Wk = (const float*)d_in[4];
    const float* bk = (const float*)d_in[5];
    const float* Wv = (const float*)d_in[6];
    const float* bv = (const float*)d_in[7];
    const float* Wo = (const float*)d_in[8];
    const float* bo = (const float*)d_in[9];
    float* out = (float*)d_out;

    short* base = (short*)d_ws;
    short* xb   = base;                      // 4096*1024
    short* wqt  = xb  + 4194304;             // 512*1024
    short* wkt  = wqt + 524288;
    short* wvt  = wkt + 524288;
    short* wot  = wvt + 524288;              // 1024*512
    short* spW  = wot + 524288;              // 16*2048*64
    short* sqW  = spW + 2097152;
    short* vtW  = sqW + 2097152;             // [b,h,d,s]
    short* attB = vtW + 2097152;             // 4096*512
    // total = 14,680,064 shorts = 28 MB

    hipLaunchKernelGGL(convert_x, dim3(4096), dim3(256), 0, stream, xr, xi, xb);
    hipLaunchKernelGGL(transpose_w, dim3(32, 32, 4), dim3(256), 0, stream,
                       Wq, Wk, Wv, Wo, wqt, wkt, wvt, wot);
    hipLaunchKernelGGL(qkv_mfma, dim3(24, 32), dim3(128), 0, stream,
                       xb, wqt, wkt, wvt, bq, bk, bv, spW, sqW, vtW);
    hipLaunchKernelGGL(attn_mfma, dim3(64, 16), dim3(256), 0, stream,
                       spW, sqW, vtW, attB);
    hipLaunchKernelGGL(out_mfma, dim3(16, 32), dim3(128), 0, stream,
                       attB, wot, bo, out);
}